// Round 16
// baseline (347.468 us; speedup 1.0000x reference)
//
#include <hip/hip_runtime.h>
#include <math.h>

#define B_   2
#define S_   2048
#define DM_  1024
#define NH_  16
#define DH_  64
#define DFF_ 4096
#define WIN_ 256
#define MTOK (B_*S_)   // 4096 tokens

typedef unsigned short ushort_t;
typedef short s16x8 __attribute__((ext_vector_type(8)));
typedef float f32x4 __attribute__((ext_vector_type(4)));

__device__ __forceinline__ float b2f(ushort_t u) {
    union { unsigned int i; float f; } c; c.i = ((unsigned int)u) << 16; return c.f;
}
__device__ __forceinline__ ushort_t f2b(float f) {
    union { float f; unsigned int i; } c; c.f = f;
    unsigned int r = c.i + 0x7fffu + ((c.i >> 16) & 1u);   // RNE
    return (ushort_t)(r >> 16);
}
// tanh-form GELU: |err| vs exact erf-GELU < 3e-3 absolute (<< bf16 noise here)
__device__ __forceinline__ float gelu_fast(float x) {
    const float u = 0.7978845608f * x * fmaf(0.044715f, x * x, 1.0f);
    const float e = __expf(2.0f * u);
    const float t = 1.0f - 2.0f / (e + 1.0f);   // tanh(u)
    return 0.5f * x * (1.0f + t);
}
__device__ __forceinline__ void gload16(const void* g, void* l) {
    __builtin_amdgcn_global_load_lds(
        (const __attribute__((address_space(1))) unsigned int*)g,
        (__attribute__((address_space(3))) unsigned int*)l, 16, 0, 0);
}
// bijective XCD-aware swizzle — attention only
__device__ __forceinline__ int xcd_swz(int wgid, int nwg) {
    const int nx = 8;
    const int q = nwg / nx, r = nwg % nx;
    const int xcd = wgid % nx, lo = wgid / nx;
    const int base = (xcd < r) ? xcd * (q + 1) : r * (q + 1) + (xcd - r) * q;
    return base + lo;
}

// ---------------------------------------------------------------------------
// bf16 MFMA GEMM main loop: 256x128 tile, BK=64, 8 waves (512 threads),
// 2-phase double-buffer + CORRECT bank swizzle.
//   LDS row = 128B = 8 x 16B blocks. Store: physical block p at row r holds
//   logical block p^(r&7) -> achieved by PRE-SWIZZLING the global source col
//   (sk = ((lane&7)^(lane>>3))*8 elems; LDS dest stays linear, rule #21).
//   Read: logical block b=(4ks+lg) of row lr is at phys b^(lr&7):
//   bank = (32*lr + 4*phys) mod 32 = 4*phys -> 8 banks x 2 lanes = free.
//   (Round-14's XOR used lr&3 == the 256B bank-wrap period -> null. Fixed.)
// BK=64 halves the per-tile barrier count vs BK=32 (16 iters, prefetch flies
// under 32 MFMAs). LDS 96KB -> 1 block/CU (measured occupancy already 1).
// ---------------------------------------------------------------------------
__device__ __forceinline__ void gemm_loop(
    const ushort_t* __restrict__ A, int lda,
    const ushort_t* __restrict__ Bt, int ldb,
    int Kc, int bx, int by, f32x4 (&acc)[4][4])
{
    __shared__ __align__(16) ushort_t As[2][256 * 64];   // 2 x 32KB
    __shared__ __align__(16) ushort_t Bs[2][128 * 64];   // 2 x 16KB

    const int tid  = threadIdx.x;
    const int lane = tid & 63;
    const int w    = tid >> 6;           // 0..7
    const int row0 = by * 256;
    const int col0 = bx * 128;

    const int srow = lane >> 3;                     // 0..7 row within chunk
    const int sk   = ((lane & 7) ^ srow) * 8;       // pre-swizzled k col
    const int wr   = (w >> 1) * 64;
    const int wc   = (w & 1) * 64;
    const int lr   = lane & 15;
    const int lg   = lane >> 4;                     // 0..3

    // chunk = 1KB = 8 rows x 64 k-elems; LDS dest linear (c*1024 + lane*16)
    auto stage = [&](int buf, int k0) {
        #pragma unroll
        for (int i = 0; i < 4; ++i) {               // A: 32 chunks
            const int c = i * 8 + w;
            const int cr = c * 8 + srow;
            gload16(A + (size_t)(row0 + cr) * lda + k0 + sk,
                    (char*)As[buf] + c * 1024);
        }
        #pragma unroll
        for (int i = 0; i < 2; ++i) {               // B: 16 chunks
            const int c = i * 8 + w;
            const int cr = c * 8 + srow;
            gload16(Bt + (size_t)(col0 + cr) * ldb + k0 + sk,
                    (char*)Bs[buf] + c * 1024);
        }
    };

    const int nk = Kc >> 6;
    stage(0, 0);
    __syncthreads();
    int cur = 0;
    for (int k = 0; k < nk; ++k) {
        if (k + 1 < nk) stage(cur ^ 1, (k + 1) << 6);   // issue-early prefetch
        #pragma unroll
        for (int ks = 0; ks < 2; ++ks) {
            s16x8 af[4], bfr[4];
            #pragma unroll
            for (int mi = 0; mi < 4; ++mi) {
                const int r = wr + mi * 16 + lr;
                af[mi] = *(const s16x8*)&As[cur][r * 64 + (((ks * 4 + lg) ^ (r & 7)) * 8)];
            }
            #pragma unroll
            for (int ni = 0; ni < 4; ++ni) {
                const int r = wc + ni * 16 + lr;
                bfr[ni] = *(const s16x8*)&Bs[cur][r * 64 + (((ks * 4 + lg) ^ (r & 7)) * 8)];
            }
            #pragma unroll
            for (int mi = 0; mi < 4; ++mi)
                #pragma unroll
                for (int ni = 0; ni < 4; ++ni)
                    acc[mi][ni] = __builtin_amdgcn_mfma_f32_16x16x32_bf16(
                        af[mi], bfr[ni], acc[mi][ni], 0, 0, 0);
        }
        __syncthreads();
        cur ^= 1;
    }
}

// ---------------------------------------------------------------------------
// QKV GEMM with fused bias + per-head LN + head-major bf16 relayout.
// ---------------------------------------------------------------------------
__global__ __launch_bounds__(512) void gemm_qkvln(
    const ushort_t* __restrict__ A, const ushort_t* __restrict__ Bt,
    const float* __restrict__ bias,
    const float* __restrict__ qg, const float* __restrict__ qb,
    const float* __restrict__ kg, const float* __restrict__ kb,
    ushort_t* __restrict__ qh, ushort_t* __restrict__ kh, ushort_t* __restrict__ vh)
{
    f32x4 acc[4][4] = {};
    gemm_loop(A, 1024, Bt, 1024, 1024, blockIdx.x, blockIdx.y, acc);

    const int lane = threadIdx.x & 63;
    const int w    = threadIdx.x >> 6;
    const int wr   = (w >> 1) * 64;
    const int wc   = (w & 1) * 64;
    const int row0 = blockIdx.y * 256;
    const int col0 = blockIdx.x * 128;
    const int crow = (lane >> 4) * 4;
    const int ccol = lane & 15;
    const int sel  = (col0 + wc) >> 10;                // 0=q, 1=k, 2=v
    const int hh   = ((col0 + wc) & 1023) >> 6;
    ushort_t* dst = (sel == 0) ? qh : (sel == 1) ? kh : vh;

    #pragma unroll
    for (int mi = 0; mi < 4; ++mi) {
        float val[4][4];                  // [ni][r]
        float s1[4] = {}, sq[4] = {};
        #pragma unroll
        for (int ni = 0; ni < 4; ++ni) {
            const float bc = bias[col0 + wc + ni * 16 + ccol];
            #pragma unroll
            for (int r = 0; r < 4; ++r) {
                const float v = acc[mi][ni][r] + bc;
                val[ni][r] = v;
                s1[r] += v;
                sq[r] = fmaf(v, v, sq[r]);
            }
        }
        if (sel < 2) {
            #pragma unroll
            for (int r = 0; r < 4; ++r) {
                #pragma unroll
                for (int m = 1; m < 16; m <<= 1) {
                    s1[r] += __shfl_xor(s1[r], m);
                    sq[r] += __shfl_xor(sq[r], m);
                }
            }
        }
        #pragma unroll
        for (int r = 0; r < 4; ++r) {
            const int r_abs = row0 + wr + mi * 16 + crow + r;
            const int bb = r_abs >> 11, ss = r_abs & 2047;
            const size_t db = (((size_t)(bb * NH_ + hh)) * S_ + ss) * 64;
            const float mean = s1[r] * 0.015625f;
            const float var  = sq[r] * 0.015625f - mean * mean;
            const float rstd = rsqrtf(var + 1e-5f);
            #pragma unroll
            for (int ni = 0; ni < 4; ++ni) {
                const int d = ni * 16 + ccol;
                float v = val[ni][r];
                if (sel == 0)      v = ((v - mean) * rstd * qg[d] + qb[d]) * 0.125f;
                else if (sel == 1) v = (v - mean) * rstd * kg[d] + kb[d];
                dst[db + d] = f2b(v);
            }
        }
    }
}

// ---------------------------------------------------------------------------
// fc1 + adapter-in fused GEMM: N = 4096 (fc1, gelu->hid) + 768 (adpt, gelu->tA)
// ---------------------------------------------------------------------------
__global__ __launch_bounds__(512) void gemm_fc1ad(
    const ushort_t* __restrict__ A, const ushort_t* __restrict__ Bt,
    const float* __restrict__ bias,
    ushort_t* __restrict__ hid, ushort_t* __restrict__ tA)
{
    f32x4 acc[4][4] = {};
    gemm_loop(A, 1024, Bt, 1024, 1024, blockIdx.x, blockIdx.y, acc);

    const int lane = threadIdx.x & 63;
    const int w    = threadIdx.x >> 6;
    const int wr   = (w >> 1) * 64;
    const int wc   = (w & 1) * 64;
    const int row0 = blockIdx.y * 256;
    const int col0 = blockIdx.x * 128;
    const int crow = (lane >> 4) * 4;
    const int ccol = lane & 15;
    const bool isad = (col0 >= 4096);
    ushort_t* D = isad ? tA : hid;
    const int stride = isad ? 768 : 4096;
    const int cb     = isad ? 4096 : 0;

    #pragma unroll
    for (int ni = 0; ni < 4; ++ni) {
        const int col = col0 + wc + ni * 16 + ccol;
        const float bc = bias[col];
        #pragma unroll
        for (int mi = 0; mi < 4; ++mi) {
            #pragma unroll
            for (int r = 0; r < 4; ++r) {
                const int row = row0 + wr + mi * 16 + crow + r;
                D[(size_t)row * stride + (col - cb)] = f2b(gelu_fast(acc[mi][ni][r] + bc));
            }
        }
    }
}

// ---------------------------------------------------------------------------
// wo with split-K=2: raw partials p0/p1 (bias+residual folded into ln_token_h)
// ---------------------------------------------------------------------------
__device__ __forceinline__ void epi_raw(
    f32x4 (&acc)[4][4], float* __restrict__ C, int N, int bx, int by)
{
    const int lane = threadIdx.x & 63;
    const int w    = threadIdx.x >> 6;
    const int wr   = (w >> 1) * 64;
    const int wc   = (w & 1) * 64;
    const int crow = (lane >> 4) * 4;
    const int ccol = lane & 15;
    #pragma unroll
    for (int ni = 0; ni < 4; ++ni) {
        const int col = bx * 128 + wc + ni * 16 + ccol;
        #pragma unroll
        for (int mi = 0; mi < 4; ++mi) {
            #pragma unroll
            for (int r = 0; r < 4; ++r) {
                const int row = by * 256 + wr + mi * 16 + crow + r;
                C[(size_t)row * N + col] = acc[mi][ni][r];
            }
        }
    }
}

__global__ __launch_bounds__(512) void gemm_wo_sk(
    const ushort_t* __restrict__ A, const ushort_t* __restrict__ Wt,
    float* __restrict__ p0, float* __restrict__ p1)
{
    const int z = blockIdx.z;
    f32x4 acc[4][4] = {};
    gemm_loop(A + z * 512, 1024, Wt + z * 512, 1024, 512, blockIdx.x, blockIdx.y, acc);
    epi_raw(acc, z ? p1 : p0, 1024, blockIdx.x, blockIdx.y);
}

// ---------------------------------------------------------------------------
// MERGED fc2 split-K + both adapter out-projections in ONE dispatch.
// z=0/1: fc2 K-halves -> raw partials p0 (d_out) / p1.
// z=2:   a256 out-proj (K=256) -> a0 + bias.  z=3: a512 (K=512) -> a1 + bias.
// 512 blocks -> adapters overlap with fc2 instead of running serially.
// Single gemm_loop call site (shared LDS instance).
// ---------------------------------------------------------------------------
__global__ __launch_bounds__(512) void gemm_fc2ad(
    const ushort_t* __restrict__ hid, const ushort_t* __restrict__ fc2T,
    const ushort_t* __restrict__ tA, const ushort_t* __restrict__ w2a,
    const ushort_t* __restrict__ w2b, const float* __restrict__ b2a,
    const float* __restrict__ b2b,
    float* __restrict__ p0, float* __restrict__ p1,
    float* __restrict__ a0, float* __restrict__ a1)
{
    const int z = blockIdx.z;
    const ushort_t* Ap;  const ushort_t* Bp;
    int lda, Kc;
    float* Cp;  const float* bp;
    if (z == 0)      { Ap = hid;        Bp = fc2T;        lda = 4096; Kc = 2048; Cp = p0; bp = nullptr; }
    else if (z == 1) { Ap = hid + 2048; Bp = fc2T + 2048; lda = 4096; Kc = 2048; Cp = p1; bp = nullptr; }
    else if (z == 2) { Ap = tA;         Bp = w2a;         lda = 768;  Kc = 256;  Cp = a0; bp = b2a; }
    else             { Ap = tA + 256;   Bp = w2b;         lda = 768;  Kc = 512;  Cp = a1; bp = b2b; }

    f32x4 acc[4][4] = {};
    gemm_loop(Ap, lda, Bp, (z < 2) ? 4096 : Kc, Kc, blockIdx.x, blockIdx.y, acc);

    const int lane = threadIdx.x & 63;
    const int w    = threadIdx.x >> 6;
    const int wr   = (w >> 1) * 64;
    const int wc   = (w & 1) * 64;
    const int crow = (lane >> 4) * 4;
    const int ccol = lane & 15;
    #pragma unroll
    for (int ni = 0; ni < 4; ++ni) {
        const int col = blockIdx.x * 128 + wc + ni * 16 + ccol;
        const float bc = bp ? bp[col] : 0.0f;
        #pragma unroll
        for (int mi = 0; mi < 4; ++mi) {
            #pragma unroll
            for (int r = 0; r < 4; ++r) {
                const int row = blockIdx.y * 256 + wr + mi * 16 + crow + r;
                Cp[(size_t)row * 1024 + col] = acc[mi][ni][r] + bc;
            }
        }
    }
}

// ---------------------------------------------------------------------------
// Consolidated prep: ALL weight transposes + bias concat + x->bf16 in ONE
// dispatch. Flat 1D grid; linear block id -> work item by range.
// ---------------------------------------------------------------------------
__device__ __forceinline__ void wtrans_core(
    const float* __restrict__ W, ushort_t* __restrict__ Wt, int K, int N,
    int bx, int by)
{
    __shared__ float tile[32][33];
    const int n0 = bx * 32, k0 = by * 32;
    const int tx = threadIdx.x & 31, ty = threadIdx.x >> 5;
    #pragma unroll
    for (int j = 0; j < 4; ++j)
        tile[ty + j * 8][tx] = W[(size_t)(k0 + ty + j * 8) * N + n0 + tx];
    __syncthreads();
    #pragma unroll
    for (int j = 0; j < 4; ++j)
        Wt[(size_t)(n0 + ty + j * 8) * K + k0 + tx] = f2b(tile[tx][ty + j * 8]);
}

#define PREP_NBLK 17940
__global__ __launch_bounds__(256) void prep_all(
    const float* wq, const float* wk, const float* wv, const float* wo,
    const float* fc1_w, const float* a256_w1, const float* a512_w1,
    const float* fc2_w, const float* a256_w2, const float* a512_w2,
    const float* bq, const float* bk, const float* bv, const float* fb,
    const float* ab1, const float* ab2,
    const float* x,
    ushort_t* WqkvT, ushort_t* WoT, ushort_t* fc1adT, ushort_t* fc2T,
    ushort_t* w2aT, ushort_t* w2bT,
    float* bqkv, float* bfc1ad, ushort_t* xb)
{
    const int id = blockIdx.x;
    if (id < 4096) {            // wq/wk/wv/wo
        const int z = id >> 10, t = id & 1023;
        const float* W = (z == 0) ? wq : (z == 1) ? wk : (z == 2) ? wv : wo;
        ushort_t* D = (z == 3) ? WoT : WqkvT + (size_t)z * 1024 * 1024;
        wtrans_core(W, D, 1024, 1024, t & 31, t >> 5);
    } else if (id < 8192) {     // fc1
        const int t = id - 4096;
        wtrans_core(fc1_w, fc1adT, 1024, 4096, t & 127, t >> 7);
    } else if (id < 8448) {     // a256_w1
        const int t = id - 8192;
        wtrans_core(a256_w1, fc1adT + (size_t)4096 * 1024, 1024, 256, t & 7, t >> 3);
    } else if (id < 8960) {     // a512_w1
        const int t = id - 8448;
        wtrans_core(a512_w1, fc1adT + (size_t)4352 * 1024, 1024, 512, t & 15, t >> 4);
    } else if (id < 13056) {    // fc2
        const int t = id - 8960;
        wtrans_core(fc2_w, fc2T, 4096, 1024, t & 31, t >> 5);
    } else if (id < 13312) {    // w2a
        const int t = id - 13056;
        wtrans_core(a256_w2, w2aT, 256, 1024, t & 31, t >> 5);
    } else if (id < 13824) {    // w2b
        const int t = id - 13312;
        wtrans_core(a512_w2, w2bT, 512, 1024, t & 31, t >> 5);
    } else if (id < 13844) {    // bias concat
        const int t = (id - 13824) * 256 + threadIdx.x;
        if (t < 1024) { bqkv[t] = bq[t]; bqkv[1024 + t] = bk[t]; bqkv[2048 + t] = bv[t]; }
        if (t < 4096)      bfc1ad[t] = fb[t];
        else if (t < 4352) bfc1ad[t] = ab1[t - 4096];
        else if (t < 4864) bfc1ad[t] = ab2[t - 4352];
    } else {                    // x -> bf16
        const int i = (id - 13844) * 256 + threadIdx.x;
        float4 v = ((const float4*)x)[i];
        ushort4 o; o.x = f2b(v.x); o.y = f2b(v.y); o.z = f2b(v.z); o.w = f2b(v.w);
        ((ushort4*)xb)[i] = o;
    }
}

// ---------------------------------------------------------------------------
// MFMA flash attention. Block = (b, h, 64 queries), 4 waves x 16 q.
// ---------------------------------------------------------------------------
__global__ __launch_bounds__(256) void attn_mfma(
    const ushort_t* __restrict__ qh, const ushort_t* __restrict__ kh,
    const ushort_t* __restrict__ vh, ushort_t* __restrict__ o)
{
    __shared__ __align__(16) ushort_t Ks[64 * 64];
    __shared__ __align__(16) ushort_t Vt[64 * 64];
    __shared__ __align__(16) ushort_t Pl[4 * 16 * 64];

    const int bid = xcd_swz(blockIdx.x, gridDim.x);
    const int qt  = bid & 31;
    const int hh  = (bid >> 5) & 15;
    const int b   = bid >> 9;
    const int wq   = threadIdx.x >> 6;
    const int lane = threadIdx.x & 63;
    const int lg  = lane >> 4;
    const int lq  = lane & 15;

    const int i0  = qt * 64;
    const int iw0 = i0 + wq * 16;
    const int i_l = iw0 + lq;

    const size_t plane = ((size_t)(b * NH_ + hh)) * S_ * 64;

    s16x8 qf[2];
    {
        const ushort_t* qp = qh + plane + (size_t)(iw0 + lq) * 64 + lg * 8;
        qf[0] = *(const s16x8*)(qp);
        qf[1] = *(const s16x8*)(qp + 32);
    }

    f32x4 acc[4] = {};
    float M = -1e30f, L = 0.0f;

    const int jstart = (i0 - WIN_) > 0 ? (i0 - WIN_) : 0;
    const int nt     = (i0 + 64 - jstart) >> 6;

    const int srow0 = threadIdx.x >> 3;
    const int sd0   = (threadIdx.x & 7) * 8;

    for (int t = 0; t < nt; ++t) {
        const int j0 = jstart + t * 64;

        #pragma unroll
        for (int pass = 0; pass < 2; ++pass) {
            const int skey = srow0 + pass * 32;
            const size_t src = plane + (size_t)(j0 + skey) * 64 + sd0;
            s16x8 k8 = *(const s16x8*)(kh + src);
            s16x8 v8 = *(const s16x8*)(vh + src);
            *(s16x8*)&Ks[skey * 64 + (sd0 ^ ((skey & 7) << 3))] = k8;
            #pragma unroll
            for (int e = 0; e < 8; ++e) {
                const int d = sd0 + e;
                Vt[d * 64 + (skey ^ (((d >> 1) & 7) << 3))] = (ushort_t)v8[e];
            }
        }
        __syncthreads();

        f32x4 sc[4];
        #pragma unroll
        for (int kt = 0; kt < 4; ++kt) {
            const int krow = kt * 16 + lq;
            const int swk = (krow & 7) << 3;
            s16x8 k0 = *(const s16x8*)&Ks[krow * 64 + ((lg * 8) ^ swk)];
            s16x8 k1 = *(const s16x8*)&Ks[krow * 64 + ((lg * 8 + 32) ^ swk)];
            f32x4 z = {};
            z = __builtin_amdgcn_mfma_f32_16x16x32_bf16(k0, qf[0], z, 0, 0, 0);
            z = __builtin_amdgcn_mfma_f32_16x16x32_bf16(k1, qf[1], z, 0, 0, 0);
            sc[kt] = z;
        }

        const bool fullv = (j0 + 63 <= iw0) && (iw0 + 15 - j0 <= WIN_);
        if (!fullv) {
            #pragma unroll
            for (int kt = 0; kt < 4; ++kt)
                #pragma unroll
                for (int r = 0; r < 4; ++r) {
                    const int jv = j0 + kt * 16 + lg * 4 + r;
                    const int dd = i_l - jv;
                    const bool ok = (dd >= 0) && (dd <= WIN_);
                    sc[kt][r] = ok ? sc[kt][r] : -1e30f;
                }
        }
        float mx = -1e30f;
        #pragma unroll
        for (int kt = 0; kt < 4; ++kt)
            #pragma unroll
            for (int r = 0; r < 4; ++r) mx = fmaxf(mx, sc[kt][r]);
        mx = fmaxf(mx, __shfl_xor(mx, 16));
        mx = fmaxf(mx, __shfl_xor(mx, 32));
        const float nM = fmaxf(M, mx);
        const float alpha = __expf(M - nM);
        M = nM;
        float ts = 0.0f;
        float ev[16];
        #pragma unroll
        for (int kt = 0; kt < 4; ++kt)
            #pragma unroll
            for (int r = 0; r < 4; ++r) {
                float e = __expf(sc[kt][r] - nM);
                if (!fullv) e = (sc[kt][r] > -1e29f) ? e : 0.0f;
                ev[kt * 4 + r] = e;
                ts += e;
            }
        ts += __shfl_xor(ts, 16);
        ts += __shfl_xor(ts, 32);
        L = L * alpha + ts;

        {
            ushort_t* pw = Pl + wq * 1024;
            const int swq = (lq & 7) << 3;
            #pragma unroll
            for (int kt = 0; kt < 4; ++kt)
                #pragma unroll
                for (int pr = 0; pr < 2; ++pr) {
                    const int key0 = kt * 16 + lg * 4 + pr * 2;
                    const unsigned int pk =
                        (unsigned int)f2b(ev[kt * 4 + pr * 2]) |
                        ((unsigned int)f2b(ev[kt * 4 + pr * 2 + 1]) << 16);
                    *(unsigned int*)&pw[lq * 64 + (key0 ^ swq)] = pk;
                }
        }

        float ar[4];
        #pragma unroll
        for (int r = 0; r < 4; ++r) ar[r] = __shfl(alpha, lg * 4 + r);
        #pragma unroll
        for (int dt = 0; dt < 4; ++dt)
            #pragma unroll
            for (int r = 0; r < 4; ++r) acc[dt][r] *= ar[r];

        {
            const ushort_t* pw = Pl + wq * 1024;
            const int swq = (lq & 7) << 3;
            s16x8 pf0 = *(const s16x8*)&pw[lq * 64 + ((lg * 8) ^ swq)];
            s16x8 pf1 = *(const s16x8*)&pw[lq * 64 + ((lg * 8 + 32) ^ swq)];
            #pragma unroll
            for (int dt = 0; dt < 4; ++dt) {
                const int d = dt * 16 + lq;
                const int swd = ((d >> 1) & 7) << 3;
                s16x8 v0 = *(const s16x8*)&Vt[d * 64 + ((lg * 8) ^ swd)];
                s16x8 v1 = *(const s16x8*)&Vt[d * 64 + ((lg * 8 + 32) ^ swd)];
                acc[dt] = __builtin_amdgcn_mfma_f32_16x16x32_bf16(pf0, v0, acc[dt], 0, 0, 0);
                acc[dt] = __builtin_amdgcn_mfma_f32_16x16x32_bf16(pf1, v1, acc[dt], 0, 0, 0);
            }
        }
        __syncthreads();
    }

    const float inv = 1.0f / L;
    float ir[4];
    #pragma unroll
    for (int r = 0; r < 4; ++r) ir[r] = __shfl(inv, lg * 4 + r);
    #pragma unroll
    for (int dt = 0; dt < 4; ++dt)
        #pragma unroll
        for (int r = 0; r < 4; ++r) {
            const int qq = lg * 4 + r;
            o[((size_t)(b * S_ + iw0 + qq)) * DM_ + hh * 64 + dt * 16 + lq] =
                f2b(acc[dt][r] * ir[r]);
        }
}

// ---------------------------------------------------------------------------
// Fused h-assembly + token LayerNorm (N=1024).
// ---------------------------------------------------------------------------
__global__ __launch_bounds__(256) void ln_token_h(
    const float* __restrict__ p0, const float* __restrict__ p1,
    const float* __restrict__ bo, const float* __restrict__ x,
    float* __restrict__ hb, ushort_t* __restrict__ xnb,
    const float* __restrict__ g, const float* __restrict__ b)
{
    const int t = blockIdx.x;
    const size_t base = (size_t)t * 1024;
    float vals[4];
    float s = 0.0f, s2 = 0.0f;
    #pragma unroll
    for (int i = 0; i < 4; ++i) {
        const int idx = i * 256 + threadIdx.x;
        const float v = x[base + idx] + p0[base + idx] + p1[base + idx] + bo[idx];
        hb[base + idx] = v;
        vals[i] = v;
        s += v;
        s2 = fmaf(v, v, s2);
    }
    #pragma unroll
    for (int o = 32; o >= 1; o >>= 1) { s += __shfl_xor(s, o); s2 += __shfl_xor(s2, o); }
    __shared__ float rs[4], rq[4];
    const int wid = threadIdx.x >> 6, lane = threadIdx.x & 63;
    if (lane == 0) { rs[wid] = s; rq[wid] = s2; }
    __syncthreads();
    s  = rs[0] + rs[1] + rs[2] + rs[3];
    s2 = rq[0] + rq[1] + rq[2] + rq[3];
    const float mean = s * (1.0f / 1024.0f);
    const float var  = s2 * (1.0f / 1024.0f) - mean * mean;
    const float rstd = rsqrtf(var + 1e-5f);
    #pragma unroll
    for (int i = 0; i < 4; ++i) {
        const int idx = i * 256 + threadIdx.x;
        xnb[base + idx] = f2b((vals[i] - mean) * rstd * g[idx] + b[idx]);
    }
}

// ---------------------------------------------------------------------------
// Token LayerNorm: bf16 in -> bf16 out. One block per token.
// ---------------------------------------------------------------------------
template <int N>
__global__ __launch_bounds__(256) void ln_token2(
    const ushort_t* __restrict__ in, ushort_t* __restrict__ outp,
    const float* __restrict__ g, const float* __restrict__ b)
{
    constexpr int NPT = N / 256;
    const int t = blockIdx.x;
    const ushort_t* row = in + (size_t)t * N;
    float vals[NPT];
    float s = 0.0f, s2 = 0.0f;
    #pragma unroll
    for (int i = 0; i < NPT; ++i) {
        float x = b2f(row[i * 256 + threadIdx.x]);
        vals[i] = x;
        s += x;
        s2 = fmaf(x, x, s2);
    }
    #pragma unroll
    for (int o = 32; o >= 1; o >>= 1) { s += __shfl_xor(s, o); s2 += __shfl_xor(s2, o); }
    __shared__ float rs[4], rq[4];
    const int wid = threadIdx.x >> 6, lane = threadIdx.x & 63;
    if (lane == 0) { rs[wid] = s; rq[wid] = s2; }
    __syncthreads();
    s  = rs[0] + rs[1] + rs[2] + rs[3];
    s2 = rq[0] + rq[1] + rq[2] + rq[3];
    const float mean = s * (1.0f / N);
    const float var  = s2 * (1.0f / N) - mean * mean;
    const float rstd = rsqrtf(var + 1e-5f);
    #pragma unroll
    for (int i = 0; i < NPT; ++i) {
        const int idx = i * 256 + threadIdx.x;
        outp[(size_t)t * N + idx] = f2b((vals[i] - mean) * rstd * g[idx] + b[idx]);
    }
}

// ---------------------------------------------------------------------------
// Final combine: out = h + (p0+p1+fc2_b)*wm + adaptive*(1-wm).
// ---------------------------------------------------------------------------
__global__ __launch_bounds__(256) void combine3(
    float* __restrict__ outp, const float* __restrict__ p1,
    const float* __restrict__ fc2b, const float* __restrict__ h,
    const ushort_t* __restrict__ xnb, const float* __restrict__ a0,
    const float* __restrict__ a1, const float* __restrict__ wm,
    const int* __restrict__ widx)
{
    const size_t idx = (size_t)blockIdx.x * 256 + threadIdx.x;
    const int t   = (int)(idx >> 10);
    const int col = (int)(idx & 1023);
    const float w = wm[t];
    const int sel = widx[t];
    const float base = outp[idx] + p1[idx] + fc2b[col];
    const float ad = (sel == 0) ? a0[idx] : ((sel == 1) ? a1[idx] : b2f(xnb[idx]));
    outp[idx] = h[idx] + base * w + ad * (1.0f - w);
}

// ---------------------------------------------------------------------------
extern "C" void kernel_launch(void* const* d_in, const int* in_sizes, int n_in,
                              void* d_out, int out_size, void* d_ws, size_t ws_size,
                              hipStream_t stream)
{
    const float* x     = (const float*)d_in[0];
    const float* wm    = (const float*)d_in[1];
    const float* wq    = (const float*)d_in[2];
    const float* bq    = (const float*)d_in[3];
    const float* wk    = (const float*)d_in[4];
    const float* bk    = (const float*)d_in[5];
    const float* wv    = (const float*)d_in[6];
    const float* bv    = (const float*)d_in[7];
    const float* wo    = (const float*)d_in[8];
    const float* bo    = (const float*)d_in[9];
    const float* lnq_g = (const float*)d_in[10];
    const float* lnq_b = (const float*)d_in[11];
    const float* lnk_g = (const float*)d_in[12];
    const float* lnk_b = (const float*)d_in[13];
    const float* fc1_w = (const float*)d_in[14];
    const float* fc1_b = (const float*)d_in[15];
    const float* fc2_w = (const float*)d_in[16];
    const float* fc2_b = (const float*)d_in[17];
    const float* lni_g = (const float*)d_in[18];
    const float* lni_b = (const float*)d_in[19];
    const float* lnh_g = (const float*)d_in[20];
    const float* lnh_b = (const float*)d_in[21];
    const float* a256_w1 = (const float*)d_in[22];
    const float* a256_b1 = (const float*)d_in[23];
    const float* a256_w2 = (const float*)d_in[24];
    const float* a256_b2 = (const float*)d_in[25];
    const float* a512_w1 = (const float*)d_in[26];
    const float* a512_b1 = (const float*)d_in[27];
    const float* a512_w2 = (const float*)d_in[28];
    const float* a512_b2 = (const float*)d_in[29];
    const int*   widx    = (const int*)d_in[30];

    float* out = (float*)d_out;

    char* p = (char*)d_ws;
    auto alloc = [&](size_t bytes) { char* r = p; p += (bytes + 255) & ~(size_t)255; return r; };
    float*    ascr  = (float*)   alloc((size_t)MTOK * 2048 * 4);  // a0/a1
    float*    hb    = (float*)   alloc((size_t)MTOK * 1024 * 4);
    ushort_t* xnb   = (ushort_t*)alloc((size_t)MTOK * 1024 * 2);
    ushort_t* hidb  = (ushort_t*)alloc((size_t)MTOK * 4096 * 2);  // xb/attnb/qh/kh alias
    ushort_t* tA    = (ushort_t*)alloc((size_t)MTOK * 768 * 2);
    ushort_t* WqkvT = (ushort_t*)alloc((size_t)3072 * 1024 * 2);
    ushort_t* WoT   = (ushort_t*)alloc((size_t)1024 * 1024 * 2);
    ushort_t* fc1adT= (ushort_t*)alloc((size_t)4864 * 1024 * 2);  // fc1 + adapter-in
    ushort_t* fc2T  = (ushort_t*)alloc((size_t)1024 * 4096 * 2);
    ushort_t* w2aT  = (ushort_t*)alloc((size_t)1024 * 256 * 2);
    ushort_t* w2bT  = (ushort_t*)alloc((size_t)1024 * 512 * 2);
    float*    bqkv  = (float*)   alloc(3072 * 4);
    float*    bfc1ad= (float*)   alloc(4864 * 4);
    float*    p1    = (float*)   alloc((size_t)MTOK * 1024 * 4);  // partials / vh alias
    // aliases (lifetimes verified, unchanged)
    ushort_t* xb    = hidb;
    ushort_t* attnb = hidb + (size_t)MTOK * 1024;
    ushort_t* qh    = hidb + (size_t)MTOK * 2048;
    ushort_t* kh    = hidb + (size_t)MTOK * 3072;
    ushort_t* vh    = (ushort_t*)p1;
    float*    a0    = ascr;
    float*    a1    = ascr + (size_t)MTOK * 1024;

    const dim3 blk(256);
    const dim3 blk512(512);

    // ---- consolidated prep ----
    prep_all<<<PREP_NBLK, blk, 0, stream>>>(
        wq, wk, wv, wo, fc1_w, a256_w1, a512_w1, fc2_w, a256_w2, a512_w2,
        bq, bk, bv, fc1_b, a256_b1, a512_b1, x,
        WqkvT, WoT, fc1adT, fc2T, w2aT, w2bT, bqkv, bfc1ad, xb);

    // ---- QKV GEMM + fused per-head LN/relayout, then MFMA attention ----
    gemm_qkvln<<<dim3(24, 16), blk512, 0, stream>>>(xb, WqkvT, bqkv,
        lnq_g, lnq_b, lnk_g, lnk_b, qh, kh, vh);
    attn_mfma<<<B_ * NH_ * (S_ / 64), blk, 0, stream>>>(qh, kh, vh, attnb);

    // ---- output projection (split-K=2) + fused residual/bias + LN ----
    gemm_wo_sk<<<dim3(8, 16, 2), blk512, 0, stream>>>(attnb, WoT, hb, p1);
    ln_token_h<<<MTOK, blk, 0, stream>>>(hb, p1, bo, x, hb, xnb, lni_g, lni_b);

    // ---- fc1 + adapter-in fused ----
    gemm_fc1ad<<<dim3(38, 16), blk512, 0, stream>>>(xnb, fc1adT, bfc1ad, hidb, tA);
    ln_token2<DFF_><<<MTOK, blk, 0, stream>>>(hidb, hidb, lnh_g, lnh_b);

    // ---- fc2 split-K + both adapter out-projections, ONE dispatch ----
    gemm_fc2ad<<<dim3(8, 16, 4), blk512, 0, stream>>>(hidb, fc2T, tA, w2aT, w2bT,
        a256_b2, a512_b2, out, p1, a0, a1);

    // ---- final routed combine ----
    combine3<<<(int)((size_t)MTOK * 1024 / 256), blk, 0, stream>>>(
        out, p1, fc2_b, hb, xnb, a0, a1, wm, widx);
}

// Round 17
// 288.096 us; speedup vs baseline: 1.2061x; 1.2061x over previous
//
#include <hip/hip_runtime.h>
#include <math.h>

#define B_   2
#define S_   2048
#define DM_  1024
#define NH_  16
#define DH_  64
#define DFF_ 4096
#define WIN_ 256
#define MTOK (B_*S_)   // 4096 tokens

typedef unsigned short ushort_t;
typedef short s16x8 __attribute__((ext_vector_type(8)));
typedef float f32x4 __attribute__((ext_vector_type(4)));

__device__ __forceinline__ float b2f(ushort_t u) {
    union { unsigned int i; float f; } c; c.i = ((unsigned int)u) << 16; return c.f;
}
__device__ __forceinline__ ushort_t f2b(float f) {
    union { float f; unsigned int i; } c; c.f = f;
    unsigned int r = c.i + 0x7fffu + ((c.i >> 16) & 1u);   // RNE
    return (ushort_t)(r >> 16);
}
// tanh-form GELU: |err| vs exact erf-GELU < 3e-3 absolute (<< bf16 noise here)
__device__ __forceinline__ float gelu_fast(float x) {
    const float u = 0.7978845608f * x * fmaf(0.044715f, x * x, 1.0f);
    const float e = __expf(2.0f * u);
    const float t = 1.0f - 2.0f / (e + 1.0f);   // tanh(u)
    return 0.5f * x * (1.0f + t);
}
__device__ __forceinline__ void gload16(const void* g, void* l) {
    __builtin_amdgcn_global_load_lds(
        (const __attribute__((address_space(1))) unsigned int*)g,
        (__attribute__((address_space(3))) unsigned int*)l, 16, 0, 0);
}
// bijective XCD-aware swizzle — attention only
__device__ __forceinline__ int xcd_swz(int wgid, int nwg) {
    const int nx = 8;
    const int q = nwg / nx, r = nwg % nx;
    const int xcd = wgid % nx, lo = wgid / nx;
    const int base = (xcd < r) ? xcd * (q + 1) : r * (q + 1) + (xcd - r) * q;
    return base + lo;
}

// ---------------------------------------------------------------------------
// bf16 MFMA GEMM main loop: 256x128 tile, BK=32, 8 waves (512 threads),
// 2-phase double-buffer (48KB LDS -> 2 blocks/CU, the best-measured regime)
// + bank swizzle verified at BK=64 (r16: conflicts 4.98e6 -> 0), re-derived
// for BK=32:
//   row = 64B = 4 x 16B blocks. Store logical block b of row r at physical
//   b ^ ((r>>1)&3): pre-swizzled global source sk = ((lane&3)^((lane>>3)&3))*8
//   with LINEAR LDS dest (rule #21); read phys = lg ^ ((lr>>1)&3).
//   Bank: 16*(lr&1) + 4*(lg^((lr>>1)&3)) -> 8 groups x 2 lanes = free (m136).
// ---------------------------------------------------------------------------
__device__ __forceinline__ void gemm_loop(
    const ushort_t* __restrict__ A, int lda,
    const ushort_t* __restrict__ Bt, int ldb,
    int Kc, int bx, int by, f32x4 (&acc)[4][4])
{
    __shared__ __align__(16) ushort_t As[2][256 * 32];   // 2 x 16KB
    __shared__ __align__(16) ushort_t Bs[2][128 * 32];   // 2 x  8KB

    const int tid  = threadIdx.x;
    const int lane = tid & 63;
    const int w    = tid >> 6;           // 0..7
    const int row0 = by * 256;
    const int col0 = bx * 128;

    const int srow = lane >> 2;                              // 0..15 row in chunk
    const int sk   = (((lane & 3) ^ ((lane >> 3) & 3)) * 8); // pre-swizzled col
    const int wr   = (w >> 1) * 64;
    const int wc   = (w & 1) * 64;
    const int lr   = lane & 15;
    const int lg   = lane >> 4;                              // 0..3
    const int lk   = ((lg ^ ((lr >> 1) & 3)) * 8);           // swizzled read col

    auto stage = [&](int buf, int k0) {
        #pragma unroll
        for (int i = 0; i < 2; ++i) {               // A: 16 chunks
            const int c = i * 8 + w;
            const int cr = c * 16 + srow;
            gload16(A + (size_t)(row0 + cr) * lda + k0 + sk,
                    (char*)As[buf] + c * 1024);
        }
        {                                            // B: 8 chunks (1/wave)
            const int cr = w * 16 + srow;
            gload16(Bt + (size_t)(col0 + cr) * ldb + k0 + sk,
                    (char*)Bs[buf] + w * 1024);
        }
    };

    const int nk = Kc >> 5;
    stage(0, 0);
    __syncthreads();
    int cur = 0;
    for (int k = 0; k < nk; ++k) {
        if (k + 1 < nk) stage(cur ^ 1, (k + 1) << 5);   // issue-early prefetch
        s16x8 af[4], bfr[4];
        #pragma unroll
        for (int mi = 0; mi < 4; ++mi)
            af[mi] = *(const s16x8*)&As[cur][(wr + mi * 16 + lr) * 32 + lk];
        #pragma unroll
        for (int ni = 0; ni < 4; ++ni)
            bfr[ni] = *(const s16x8*)&Bs[cur][(wc + ni * 16 + lr) * 32 + lk];
        #pragma unroll
        for (int mi = 0; mi < 4; ++mi)
            #pragma unroll
            for (int ni = 0; ni < 4; ++ni)
                acc[mi][ni] = __builtin_amdgcn_mfma_f32_16x16x32_bf16(
                    af[mi], bfr[ni], acc[mi][ni], 0, 0, 0);
        __syncthreads();
        cur ^= 1;
    }
}

// ---------------------------------------------------------------------------
// QKV GEMM with fused bias + per-head LN + head-major bf16 relayout.
// ---------------------------------------------------------------------------
__global__ __launch_bounds__(512) void gemm_qkvln(
    const ushort_t* __restrict__ A, const ushort_t* __restrict__ Bt,
    const float* __restrict__ bias,
    const float* __restrict__ qg, const float* __restrict__ qb,
    const float* __restrict__ kg, const float* __restrict__ kb,
    ushort_t* __restrict__ qh, ushort_t* __restrict__ kh, ushort_t* __restrict__ vh)
{
    f32x4 acc[4][4] = {};
    gemm_loop(A, 1024, Bt, 1024, 1024, blockIdx.x, blockIdx.y, acc);

    const int lane = threadIdx.x & 63;
    const int w    = threadIdx.x >> 6;
    const int wr   = (w >> 1) * 64;
    const int wc   = (w & 1) * 64;
    const int row0 = blockIdx.y * 256;
    const int col0 = blockIdx.x * 128;
    const int crow = (lane >> 4) * 4;
    const int ccol = lane & 15;
    const int sel  = (col0 + wc) >> 10;                // 0=q, 1=k, 2=v
    const int hh   = ((col0 + wc) & 1023) >> 6;
    ushort_t* dst = (sel == 0) ? qh : (sel == 1) ? kh : vh;

    #pragma unroll
    for (int mi = 0; mi < 4; ++mi) {
        float val[4][4];                  // [ni][r]
        float s1[4] = {}, sq[4] = {};
        #pragma unroll
        for (int ni = 0; ni < 4; ++ni) {
            const float bc = bias[col0 + wc + ni * 16 + ccol];
            #pragma unroll
            for (int r = 0; r < 4; ++r) {
                const float v = acc[mi][ni][r] + bc;
                val[ni][r] = v;
                s1[r] += v;
                sq[r] = fmaf(v, v, sq[r]);
            }
        }
        if (sel < 2) {
            #pragma unroll
            for (int r = 0; r < 4; ++r) {
                #pragma unroll
                for (int m = 1; m < 16; m <<= 1) {
                    s1[r] += __shfl_xor(s1[r], m);
                    sq[r] += __shfl_xor(sq[r], m);
                }
            }
        }
        #pragma unroll
        for (int r = 0; r < 4; ++r) {
            const int r_abs = row0 + wr + mi * 16 + crow + r;
            const int bb = r_abs >> 11, ss = r_abs & 2047;
            const size_t db = (((size_t)(bb * NH_ + hh)) * S_ + ss) * 64;
            const float mean = s1[r] * 0.015625f;
            const float var  = sq[r] * 0.015625f - mean * mean;
            const float rstd = rsqrtf(var + 1e-5f);
            #pragma unroll
            for (int ni = 0; ni < 4; ++ni) {
                const int d = ni * 16 + ccol;
                float v = val[ni][r];
                if (sel == 0)      v = ((v - mean) * rstd * qg[d] + qb[d]) * 0.125f;
                else if (sel == 1) v = (v - mean) * rstd * kg[d] + kb[d];
                dst[db + d] = f2b(v);
            }
        }
    }
}

// ---------------------------------------------------------------------------
// fc1 + adapter-in fused GEMM: N = 4096 (fc1, gelu->hid) + 768 (adpt, gelu->tA)
// ---------------------------------------------------------------------------
__global__ __launch_bounds__(512) void gemm_fc1ad(
    const ushort_t* __restrict__ A, const ushort_t* __restrict__ Bt,
    const float* __restrict__ bias,
    ushort_t* __restrict__ hid, ushort_t* __restrict__ tA)
{
    f32x4 acc[4][4] = {};
    gemm_loop(A, 1024, Bt, 1024, 1024, blockIdx.x, blockIdx.y, acc);

    const int lane = threadIdx.x & 63;
    const int w    = threadIdx.x >> 6;
    const int wr   = (w >> 1) * 64;
    const int wc   = (w & 1) * 64;
    const int row0 = blockIdx.y * 256;
    const int col0 = blockIdx.x * 128;
    const int crow = (lane >> 4) * 4;
    const int ccol = lane & 15;
    const bool isad = (col0 >= 4096);
    ushort_t* D = isad ? tA : hid;
    const int stride = isad ? 768 : 4096;
    const int cb     = isad ? 4096 : 0;

    #pragma unroll
    for (int ni = 0; ni < 4; ++ni) {
        const int col = col0 + wc + ni * 16 + ccol;
        const float bc = bias[col];
        #pragma unroll
        for (int mi = 0; mi < 4; ++mi) {
            #pragma unroll
            for (int r = 0; r < 4; ++r) {
                const int row = row0 + wr + mi * 16 + crow + r;
                D[(size_t)row * stride + (col - cb)] = f2b(gelu_fast(acc[mi][ni][r] + bc));
            }
        }
    }
}

// ---------------------------------------------------------------------------
// wo with split-K=2: raw partials p0/p1 (bias+residual folded into ln_token_h)
// ---------------------------------------------------------------------------
__device__ __forceinline__ void epi_raw(
    f32x4 (&acc)[4][4], float* __restrict__ C, int N, int bx, int by)
{
    const int lane = threadIdx.x & 63;
    const int w    = threadIdx.x >> 6;
    const int wr   = (w >> 1) * 64;
    const int wc   = (w & 1) * 64;
    const int crow = (lane >> 4) * 4;
    const int ccol = lane & 15;
    #pragma unroll
    for (int ni = 0; ni < 4; ++ni) {
        const int col = bx * 128 + wc + ni * 16 + ccol;
        #pragma unroll
        for (int mi = 0; mi < 4; ++mi) {
            #pragma unroll
            for (int r = 0; r < 4; ++r) {
                const int row = by * 256 + wr + mi * 16 + crow + r;
                C[(size_t)row * N + col] = acc[mi][ni][r];
            }
        }
    }
}

__global__ __launch_bounds__(512) void gemm_wo_sk(
    const ushort_t* __restrict__ A, const ushort_t* __restrict__ Wt,
    float* __restrict__ p0, float* __restrict__ p1)
{
    const int z = blockIdx.z;
    f32x4 acc[4][4] = {};
    gemm_loop(A + z * 512, 1024, Wt + z * 512, 1024, 512, blockIdx.x, blockIdx.y, acc);
    epi_raw(acc, z ? p1 : p0, 1024, blockIdx.x, blockIdx.y);
}

// ---------------------------------------------------------------------------
// MERGED fc2 split-K + both adapter out-projections in ONE dispatch.
// ---------------------------------------------------------------------------
__global__ __launch_bounds__(512) void gemm_fc2ad(
    const ushort_t* __restrict__ hid, const ushort_t* __restrict__ fc2T,
    const ushort_t* __restrict__ tA, const ushort_t* __restrict__ w2a,
    const ushort_t* __restrict__ w2b, const float* __restrict__ b2a,
    const float* __restrict__ b2b,
    float* __restrict__ p0, float* __restrict__ p1,
    float* __restrict__ a0, float* __restrict__ a1)
{
    const int z = blockIdx.z;
    const ushort_t* Ap;  const ushort_t* Bp;
    int lda, ldb, Kc;
    float* Cp;  const float* bp;
    if (z == 0)      { Ap = hid;        Bp = fc2T;        lda = 4096; ldb = 4096; Kc = 2048; Cp = p0; bp = nullptr; }
    else if (z == 1) { Ap = hid + 2048; Bp = fc2T + 2048; lda = 4096; ldb = 4096; Kc = 2048; Cp = p1; bp = nullptr; }
    else if (z == 2) { Ap = tA;         Bp = w2a;         lda = 768;  ldb = 256;  Kc = 256;  Cp = a0; bp = b2a; }
    else             { Ap = tA + 256;   Bp = w2b;         lda = 768;  ldb = 512;  Kc = 512;  Cp = a1; bp = b2b; }

    f32x4 acc[4][4] = {};
    gemm_loop(Ap, lda, Bp, ldb, Kc, blockIdx.x, blockIdx.y, acc);

    const int lane = threadIdx.x & 63;
    const int w    = threadIdx.x >> 6;
    const int wr   = (w >> 1) * 64;
    const int wc   = (w & 1) * 64;
    const int crow = (lane >> 4) * 4;
    const int ccol = lane & 15;
    #pragma unroll
    for (int ni = 0; ni < 4; ++ni) {
        const int col = blockIdx.x * 128 + wc + ni * 16 + ccol;
        const float bc = bp ? bp[col] : 0.0f;
        #pragma unroll
        for (int mi = 0; mi < 4; ++mi) {
            #pragma unroll
            for (int r = 0; r < 4; ++r) {
                const int row = blockIdx.y * 256 + wr + mi * 16 + crow + r;
                Cp[(size_t)row * 1024 + col] = acc[mi][ni][r] + bc;
            }
        }
    }
}

// ---------------------------------------------------------------------------
// Consolidated prep: ALL weight transposes + bias concat + x->bf16 in ONE
// dispatch. Flat 1D grid; linear block id -> work item by range.
// ---------------------------------------------------------------------------
__device__ __forceinline__ void wtrans_core(
    const float* __restrict__ W, ushort_t* __restrict__ Wt, int K, int N,
    int bx, int by)
{
    __shared__ float tile[32][33];
    const int n0 = bx * 32, k0 = by * 32;
    const int tx = threadIdx.x & 31, ty = threadIdx.x >> 5;
    #pragma unroll
    for (int j = 0; j < 4; ++j)
        tile[ty + j * 8][tx] = W[(size_t)(k0 + ty + j * 8) * N + n0 + tx];
    __syncthreads();
    #pragma unroll
    for (int j = 0; j < 4; ++j)
        Wt[(size_t)(n0 + ty + j * 8) * K + k0 + tx] = f2b(tile[tx][ty + j * 8]);
}

#define PREP_NBLK 17940
__global__ __launch_bounds__(256) void prep_all(
    const float* wq, const float* wk, const float* wv, const float* wo,
    const float* fc1_w, const float* a256_w1, const float* a512_w1,
    const float* fc2_w, const float* a256_w2, const float* a512_w2,
    const float* bq, const float* bk, const float* bv, const float* fb,
    const float* ab1, const float* ab2,
    const float* x,
    ushort_t* WqkvT, ushort_t* WoT, ushort_t* fc1adT, ushort_t* fc2T,
    ushort_t* w2aT, ushort_t* w2bT,
    float* bqkv, float* bfc1ad, ushort_t* xb)
{
    const int id = blockIdx.x;
    if (id < 4096) {            // wq/wk/wv/wo
        const int z = id >> 10, t = id & 1023;
        const float* W = (z == 0) ? wq : (z == 1) ? wk : (z == 2) ? wv : wo;
        ushort_t* D = (z == 3) ? WoT : WqkvT + (size_t)z * 1024 * 1024;
        wtrans_core(W, D, 1024, 1024, t & 31, t >> 5);
    } else if (id < 8192) {     // fc1
        const int t = id - 4096;
        wtrans_core(fc1_w, fc1adT, 1024, 4096, t & 127, t >> 7);
    } else if (id < 8448) {     // a256_w1
        const int t = id - 8192;
        wtrans_core(a256_w1, fc1adT + (size_t)4096 * 1024, 1024, 256, t & 7, t >> 3);
    } else if (id < 8960) {     // a512_w1
        const int t = id - 8448;
        wtrans_core(a512_w1, fc1adT + (size_t)4352 * 1024, 1024, 512, t & 15, t >> 4);
    } else if (id < 13056) {    // fc2
        const int t = id - 8960;
        wtrans_core(fc2_w, fc2T, 4096, 1024, t & 31, t >> 5);
    } else if (id < 13312) {    // w2a
        const int t = id - 13056;
        wtrans_core(a256_w2, w2aT, 256, 1024, t & 31, t >> 5);
    } else if (id < 13824) {    // w2b
        const int t = id - 13312;
        wtrans_core(a512_w2, w2bT, 512, 1024, t & 31, t >> 5);
    } else if (id < 13844) {    // bias concat
        const int t = (id - 13824) * 256 + threadIdx.x;
        if (t < 1024) { bqkv[t] = bq[t]; bqkv[1024 + t] = bk[t]; bqkv[2048 + t] = bv[t]; }
        if (t < 4096)      bfc1ad[t] = fb[t];
        else if (t < 4352) bfc1ad[t] = ab1[t - 4096];
        else if (t < 4864) bfc1ad[t] = ab2[t - 4352];
    } else {                    // x -> bf16
        const int i = (id - 13844) * 256 + threadIdx.x;
        float4 v = ((const float4*)x)[i];
        ushort4 o; o.x = f2b(v.x); o.y = f2b(v.y); o.z = f2b(v.z); o.w = f2b(v.w);
        ((ushort4*)xb)[i] = o;
    }
}

// ---------------------------------------------------------------------------
// MFMA flash attention. Block = (b, h, 64 queries), 4 waves x 16 q.
// ---------------------------------------------------------------------------
__global__ __launch_bounds__(256) void attn_mfma(
    const ushort_t* __restrict__ qh, const ushort_t* __restrict__ kh,
    const ushort_t* __restrict__ vh, ushort_t* __restrict__ o)
{
    __shared__ __align__(16) ushort_t Ks[64 * 64];
    __shared__ __align__(16) ushort_t Vt[64 * 64];
    __shared__ __align__(16) ushort_t Pl[4 * 16 * 64];

    const int bid = xcd_swz(blockIdx.x, gridDim.x);
    const int qt  = bid & 31;
    const int hh  = (bid >> 5) & 15;
    const int b   = bid >> 9;
    const int wq   = threadIdx.x >> 6;
    const int lane = threadIdx.x & 63;
    const int lg  = lane >> 4;
    const int lq  = lane & 15;

    const int i0  = qt * 64;
    const int iw0 = i0 + wq * 16;
    const int i_l = iw0 + lq;

    const size_t plane = ((size_t)(b * NH_ + hh)) * S_ * 64;

    s16x8 qf[2];
    {
        const ushort_t* qp = qh + plane + (size_t)(iw0 + lq) * 64 + lg * 8;
        qf[0] = *(const s16x8*)(qp);
        qf[1] = *(const s16x8*)(qp + 32);
    }

    f32x4 acc[4] = {};
    float M = -1e30f, L = 0.0f;

    const int jstart = (i0 - WIN_) > 0 ? (i0 - WIN_) : 0;
    const int nt     = (i0 + 64 - jstart) >> 6;

    const int srow0 = threadIdx.x >> 3;
    const int sd0   = (threadIdx.x & 7) * 8;

    for (int t = 0; t < nt; ++t) {
        const int j0 = jstart + t * 64;

        #pragma unroll
        for (int pass = 0; pass < 2; ++pass) {
            const int skey = srow0 + pass * 32;
            const size_t src = plane + (size_t)(j0 + skey) * 64 + sd0;
            s16x8 k8 = *(const s16x8*)(kh + src);
            s16x8 v8 = *(const s16x8*)(vh + src);
            *(s16x8*)&Ks[skey * 64 + (sd0 ^ ((skey & 7) << 3))] = k8;
            #pragma unroll
            for (int e = 0; e < 8; ++e) {
                const int d = sd0 + e;
                Vt[d * 64 + (skey ^ (((d >> 1) & 7) << 3))] = (ushort_t)v8[e];
            }
        }
        __syncthreads();

        f32x4 sc[4];
        #pragma unroll
        for (int kt = 0; kt < 4; ++kt) {
            const int krow = kt * 16 + lq;
            const int swk = (krow & 7) << 3;
            s16x8 k0 = *(const s16x8*)&Ks[krow * 64 + ((lg * 8) ^ swk)];
            s16x8 k1 = *(const s16x8*)&Ks[krow * 64 + ((lg * 8 + 32) ^ swk)];
            f32x4 z = {};
            z = __builtin_amdgcn_mfma_f32_16x16x32_bf16(k0, qf[0], z, 0, 0, 0);
            z = __builtin_amdgcn_mfma_f32_16x16x32_bf16(k1, qf[1], z, 0, 0, 0);
            sc[kt] = z;
        }

        const bool fullv = (j0 + 63 <= iw0) && (iw0 + 15 - j0 <= WIN_);
        if (!fullv) {
            #pragma unroll
            for (int kt = 0; kt < 4; ++kt)
                #pragma unroll
                for (int r = 0; r < 4; ++r) {
                    const int jv = j0 + kt * 16 + lg * 4 + r;
                    const int dd = i_l - jv;
                    const bool ok = (dd >= 0) && (dd <= WIN_);
                    sc[kt][r] = ok ? sc[kt][r] : -1e30f;
                }
        }
        float mx = -1e30f;
        #pragma unroll
        for (int kt = 0; kt < 4; ++kt)
            #pragma unroll
            for (int r = 0; r < 4; ++r) mx = fmaxf(mx, sc[kt][r]);
        mx = fmaxf(mx, __shfl_xor(mx, 16));
        mx = fmaxf(mx, __shfl_xor(mx, 32));
        const float nM = fmaxf(M, mx);
        const float alpha = __expf(M - nM);
        M = nM;
        float ts = 0.0f;
        float ev[16];
        #pragma unroll
        for (int kt = 0; kt < 4; ++kt)
            #pragma unroll
            for (int r = 0; r < 4; ++r) {
                float e = __expf(sc[kt][r] - nM);
                if (!fullv) e = (sc[kt][r] > -1e29f) ? e : 0.0f;
                ev[kt * 4 + r] = e;
                ts += e;
            }
        ts += __shfl_xor(ts, 16);
        ts += __shfl_xor(ts, 32);
        L = L * alpha + ts;

        {
            ushort_t* pw = Pl + wq * 1024;
            const int swq = (lq & 7) << 3;
            #pragma unroll
            for (int kt = 0; kt < 4; ++kt)
                #pragma unroll
                for (int pr = 0; pr < 2; ++pr) {
                    const int key0 = kt * 16 + lg * 4 + pr * 2;
                    const unsigned int pk =
                        (unsigned int)f2b(ev[kt * 4 + pr * 2]) |
                        ((unsigned int)f2b(ev[kt * 4 + pr * 2 + 1]) << 16);
                    *(unsigned int*)&pw[lq * 64 + (key0 ^ swq)] = pk;
                }
        }

        float ar[4];
        #pragma unroll
        for (int r = 0; r < 4; ++r) ar[r] = __shfl(alpha, lg * 4 + r);
        #pragma unroll
        for (int dt = 0; dt < 4; ++dt)
            #pragma unroll
            for (int r = 0; r < 4; ++r) acc[dt][r] *= ar[r];

        {
            const ushort_t* pw = Pl + wq * 1024;
            const int swq = (lq & 7) << 3;
            s16x8 pf0 = *(const s16x8*)&pw[lq * 64 + ((lg * 8) ^ swq)];
            s16x8 pf1 = *(const s16x8*)&pw[lq * 64 + ((lg * 8 + 32) ^ swq)];
            #pragma unroll
            for (int dt = 0; dt < 4; ++dt) {
                const int d = dt * 16 + lq;
                const int swd = ((d >> 1) & 7) << 3;
                s16x8 v0 = *(const s16x8*)&Vt[d * 64 + ((lg * 8) ^ swd)];
                s16x8 v1 = *(const s16x8*)&Vt[d * 64 + ((lg * 8 + 32) ^ swd)];
                acc[dt] = __builtin_amdgcn_mfma_f32_16x16x32_bf16(pf0, v0, acc[dt], 0, 0, 0);
                acc[dt] = __builtin_amdgcn_mfma_f32_16x16x32_bf16(pf1, v1, acc[dt], 0, 0, 0);
            }
        }
        __syncthreads();
    }

    const float inv = 1.0f / L;
    float ir[4];
    #pragma unroll
    for (int r = 0; r < 4; ++r) ir[r] = __shfl(inv, lg * 4 + r);
    #pragma unroll
    for (int dt = 0; dt < 4; ++dt)
        #pragma unroll
        for (int r = 0; r < 4; ++r) {
            const int qq = lg * 4 + r;
            o[((size_t)(b * S_ + iw0 + qq)) * DM_ + hh * 64 + dt * 16 + lq] =
                f2b(acc[dt][r] * ir[r]);
        }
}

// ---------------------------------------------------------------------------
// Fused h-assembly + token LayerNorm (N=1024).
// ---------------------------------------------------------------------------
__global__ __launch_bounds__(256) void ln_token_h(
    const float* __restrict__ p0, const float* __restrict__ p1,
    const float* __restrict__ bo, const float* __restrict__ x,
    float* __restrict__ hb, ushort_t* __restrict__ xnb,
    const float* __restrict__ g, const float* __restrict__ b)
{
    const int t = blockIdx.x;
    const size_t base = (size_t)t * 1024;
    float vals[4];
    float s = 0.0f, s2 = 0.0f;
    #pragma unroll
    for (int i = 0; i < 4; ++i) {
        const int idx = i * 256 + threadIdx.x;
        const float v = x[base + idx] + p0[base + idx] + p1[base + idx] + bo[idx];
        hb[base + idx] = v;
        vals[i] = v;
        s += v;
        s2 = fmaf(v, v, s2);
    }
    #pragma unroll
    for (int o = 32; o >= 1; o >>= 1) { s += __shfl_xor(s, o); s2 += __shfl_xor(s2, o); }
    __shared__ float rs[4], rq[4];
    const int wid = threadIdx.x >> 6, lane = threadIdx.x & 63;
    if (lane == 0) { rs[wid] = s; rq[wid] = s2; }
    __syncthreads();
    s  = rs[0] + rs[1] + rs[2] + rs[3];
    s2 = rq[0] + rq[1] + rq[2] + rq[3];
    const float mean = s * (1.0f / 1024.0f);
    const float var  = s2 * (1.0f / 1024.0f) - mean * mean;
    const float rstd = rsqrtf(var + 1e-5f);
    #pragma unroll
    for (int i = 0; i < 4; ++i) {
        const int idx = i * 256 + threadIdx.x;
        xnb[base + idx] = f2b((vals[i] - mean) * rstd * g[idx] + b[idx]);
    }
}

// ---------------------------------------------------------------------------
// Token LayerNorm: bf16 in -> bf16 out. One block per token.
// ---------------------------------------------------------------------------
template <int N>
__global__ __launch_bounds__(256) void ln_token2(
    const ushort_t* __restrict__ in, ushort_t* __restrict__ outp,
    const float* __restrict__ g, const float* __restrict__ b)
{
    constexpr int NPT = N / 256;
    const int t = blockIdx.x;
    const ushort_t* row = in + (size_t)t * N;
    float vals[NPT];
    float s = 0.0f, s2 = 0.0f;
    #pragma unroll
    for (int i = 0; i < NPT; ++i) {
        float x = b2f(row[i * 256 + threadIdx.x]);
        vals[i] = x;
        s += x;
        s2 = fmaf(x, x, s2);
    }
    #pragma unroll
    for (int o = 32; o >= 1; o >>= 1) { s += __shfl_xor(s, o); s2 += __shfl_xor(s2, o); }
    __shared__ float rs[4], rq[4];
    const int wid = threadIdx.x >> 6, lane = threadIdx.x & 63;
    if (lane == 0) { rs[wid] = s; rq[wid] = s2; }
    __syncthreads();
    s  = rs[0] + rs[1] + rs[2] + rs[3];
    s2 = rq[0] + rq[1] + rq[2] + rq[3];
    const float mean = s * (1.0f / N);
    const float var  = s2 * (1.0f / N) - mean * mean;
    const float rstd = rsqrtf(var + 1e-5f);
    #pragma unroll
    for (int i = 0; i < NPT; ++i) {
        const int idx = i * 256 + threadIdx.x;
        outp[(size_t)t * N + idx] = f2b((vals[i] - mean) * rstd * g[idx] + b[idx]);
    }
}

// ---------------------------------------------------------------------------
// Final combine: out = h + (p0+p1+fc2_b)*wm + adaptive*(1-wm).
// ---------------------------------------------------------------------------
__global__ __launch_bounds__(256) void combine3(
    float* __restrict__ outp, const float* __restrict__ p1,
    const float* __restrict__ fc2b, const float* __restrict__ h,
    const ushort_t* __restrict__ xnb, const float* __restrict__ a0,
    const float* __restrict__ a1, const float* __restrict__ wm,
    const int* __restrict__ widx)
{
    const size_t idx = (size_t)blockIdx.x * 256 + threadIdx.x;
    const int t   = (int)(idx >> 10);
    const int col = (int)(idx & 1023);
    const float w = wm[t];
    const int sel = widx[t];
    const float base = outp[idx] + p1[idx] + fc2b[col];
    const float ad = (sel == 0) ? a0[idx] : ((sel == 1) ? a1[idx] : b2f(xnb[idx]));
    outp[idx] = h[idx] + base * w + ad * (1.0f - w);
}

// ---------------------------------------------------------------------------
extern "C" void kernel_launch(void* const* d_in, const int* in_sizes, int n_in,
                              void* d_out, int out_size, void* d_ws, size_t ws_size,
                              hipStream_t stream)
{
    const float* x     = (const float*)d_in[0];
    const float* wm    = (const float*)d_in[1];
    const float* wq    = (const float*)d_in[2];
    const float* bq    = (const float*)d_in[3];
    const float* wk    = (const float*)d_in[4];
    const float* bk    = (const float*)d_in[5];
    const float* wv    = (const float*)d_in[6];
    const float* bv    = (const float*)d_in[7];
    const float* wo    = (const float*)d_in[8];
    const float* bo    = (const float*)d_in[9];
    const float* lnq_g = (const float*)d_in[10];
    const float* lnq_b = (const float*)d_in[11];
    const float* lnk_g = (const float*)d_in[12];
    const float* lnk_b = (const float*)d_in[13];
    const float* fc1_w = (const float*)d_in[14];
    const float* fc1_b = (const float*)d_in[15];
    const float* fc2_w = (const float*)d_in[16];
    const float* fc2_b = (const float*)d_in[17];
    const float* lni_g = (const float*)d_in[18];
    const float* lni_b = (const float*)d_in[19];
    const float* lnh_g = (const float*)d_in[20];
    const float* lnh_b = (const float*)d_in[21];
    const float* a256_w1 = (const float*)d_in[22];
    const float* a256_b1 = (const float*)d_in[23];
    const float* a256_w2 = (const float*)d_in[24];
    const float* a256_b2 = (const float*)d_in[25];
    const float* a512_w1 = (const float*)d_in[26];
    const float* a512_b1 = (const float*)d_in[27];
    const float* a512_w2 = (const float*)d_in[28];
    const float* a512_b2 = (const float*)d_in[29];
    const int*   widx    = (const int*)d_in[30];

    float* out = (float*)d_out;

    char* p = (char*)d_ws;
    auto alloc = [&](size_t bytes) { char* r = p; p += (bytes + 255) & ~(size_t)255; return r; };
    float*    ascr  = (float*)   alloc((size_t)MTOK * 2048 * 4);  // a0/a1
    float*    hb    = (float*)   alloc((size_t)MTOK * 1024 * 4);
    ushort_t* xnb   = (ushort_t*)alloc((size_t)MTOK * 1024 * 2);
    ushort_t* hidb  = (ushort_t*)alloc((size_t)MTOK * 4096 * 2);  // xb/attnb/qh/kh alias
    ushort_t* tA    = (ushort_t*)alloc((size_t)MTOK * 768 * 2);
    ushort_t* WqkvT = (ushort_t*)alloc((size_t)3072 * 1024 * 2);
    ushort_t* WoT   = (ushort_t*)alloc((size_t)1024 * 1024 * 2);
    ushort_t* fc1adT= (ushort_t*)alloc((size_t)4864 * 1024 * 2);  // fc1 + adapter-in
    ushort_t* fc2T  = (ushort_t*)alloc((size_t)1024 * 4096 * 2);
    ushort_t* w2aT  = (ushort_t*)alloc((size_t)1024 * 256 * 2);
    ushort_t* w2bT  = (ushort_t*)alloc((size_t)1024 * 512 * 2);
    float*    bqkv  = (float*)   alloc(3072 * 4);
    float*    bfc1ad= (float*)   alloc(4864 * 4);
    float*    p1    = (float*)   alloc((size_t)MTOK * 1024 * 4);  // partials / vh alias
    // aliases (lifetimes verified, unchanged)
    ushort_t* xb    = hidb;
    ushort_t* attnb = hidb + (size_t)MTOK * 1024;
    ushort_t* qh    = hidb + (size_t)MTOK * 2048;
    ushort_t* kh    = hidb + (size_t)MTOK * 3072;
    ushort_t* vh    = (ushort_t*)p1;
    float*    a0    = ascr;
    float*    a1    = ascr + (size_t)MTOK * 1024;

    const dim3 blk(256);
    const dim3 blk512(512);

    // ---- consolidated prep ----
    prep_all<<<PREP_NBLK, blk, 0, stream>>>(
        wq, wk, wv, wo, fc1_w, a256_w1, a512_w1, fc2_w, a256_w2, a512_w2,
        bq, bk, bv, fc1_b, a256_b1, a512_b1, x,
        WqkvT, WoT, fc1adT, fc2T, w2aT, w2bT, bqkv, bfc1ad, xb);

    // ---- QKV GEMM + fused per-head LN/relayout, then MFMA attention ----
    gemm_qkvln<<<dim3(24, 16), blk512, 0, stream>>>(xb, WqkvT, bqkv,
        lnq_g, lnq_b, lnk_g, lnk_b, qh, kh, vh);
    attn_mfma<<<B_ * NH_ * (S_ / 64), blk, 0, stream>>>(qh, kh, vh, attnb);

    // ---- output projection (split-K=2) + fused residual/bias + LN ----
    gemm_wo_sk<<<dim3(8, 16, 2), blk512, 0, stream>>>(attnb, WoT, hb, p1);
    ln_token_h<<<MTOK, blk, 0, stream>>>(hb, p1, bo, x, hb, xnb, lni_g, lni_b);

    // ---- fc1 + adapter-in fused ----
    gemm_fc1ad<<<dim3(38, 16), blk512, 0, stream>>>(xnb, fc1adT, bfc1ad, hidb, tA);
    ln_token2<DFF_><<<MTOK, blk, 0, stream>>>(hidb, hidb, lnh_g, lnh_b);

    // ---- fc2 split-K + both adapter out-projections, ONE dispatch ----
    gemm_fc2ad<<<dim3(8, 16, 4), blk512, 0, stream>>>(hidb, fc2T, tA, w2aT, w2bT,
        a256_b2, a512_b2, out, p1, a0, a1);

    // ---- final routed combine ----
    combine3<<<(int)((size_t)MTOK * 1024 / 256), blk, 0, stream>>>(
        out, p1, fc2_b, hb, xnb, a0, a1, wm, widx);
}